// Round 4
// baseline (109.387 us; speedup 1.0000x reference)
//
#include <hip/hip_runtime.h>
#include <math.h>

#define NPOS 512
#define DIM  512
#define NB   1024
#define EPSV 1e-5f
#define COS_EPS 1e-8f

// ws float offsets
#define OFF_INV 0                      // [1024] inv norms, allv order [pos;neg]
#define OFF_T1  1024                   // [512]  pos . w1
#define OFF_T2  1536                   // [1024] allv . w2
#define OFF_P   2560                   // partial buffers
#define PSZ     (NPOS * NB)            // 524288 floats each
// S partial z (z=0..3): ws + OFF_P + z*PSZ          (raw dot, cols = allv m)
// T partial z (z=0..3): ws + OFF_P + (4+z)*PSZ      (t3)

__device__ __forceinline__ float softplus_f(float x) {
    return fmaxf(x, 0.f) + __logf(1.f + __expf(-fabsf(x)));
}

// ---------------- Kernel 1: norms + t1 + t2 + zero out ----------------
__global__ __launch_bounds__(256) void prep_kernel(
    const float* __restrict__ pos, const float* __restrict__ neg,
    const float* __restrict__ w, float* __restrict__ ws, float* __restrict__ out)
{
    int gtid = blockIdx.x * 256 + threadIdx.x;
    if (gtid == 0) out[0] = 0.f;
    int row  = gtid >> 6;     // one wave per row, 1024 rows (allv order)
    int lane = threadIdx.x & 63;
    if (row >= NB) return;
    bool is_pos = row < NPOS;
    const float* r = is_pos ? pos + row * DIM : neg + (row - NPOS) * DIM;

    const float4* r4  = (const float4*)r + lane * 2;
    const float4* w14 = (const float4*)(w) + lane * 2;
    const float4* w24 = (const float4*)(w + DIM) + lane * 2;
    float4 a0 = r4[0],  a1 = r4[1];
    float4 u0 = w14[0], u1 = w14[1];
    float4 v0 = w24[0], v1 = w24[1];

    float ss  = a0.x*a0.x + a0.y*a0.y + a0.z*a0.z + a0.w*a0.w
              + a1.x*a1.x + a1.y*a1.y + a1.z*a1.z + a1.w*a1.w;
    float dw1 = a0.x*u0.x + a0.y*u0.y + a0.z*u0.z + a0.w*u0.w
              + a1.x*u1.x + a1.y*u1.y + a1.z*u1.z + a1.w*u1.w;
    float dw2 = a0.x*v0.x + a0.y*v0.y + a0.z*v0.z + a0.w*v0.w
              + a1.x*v1.x + a1.y*v1.y + a1.z*v1.z + a1.w*v1.w;

    #pragma unroll
    for (int off = 32; off; off >>= 1) {
        ss  += __shfl_xor(ss, off);
        dw1 += __shfl_xor(dw1, off);
        dw2 += __shfl_xor(dw2, off);
    }
    if (lane == 0) {
        float inv = 1.f / fmaxf(sqrtf(ss), COS_EPS);
        ws[OFF_INV + row] = inv;
        ws[OFF_T2 + row]  = dw2;
        if (is_pos) ws[OFF_T1 + row] = dw1;
    }
}

// ---------------- Kernel 2: fused cos + t3 partials ----------------
// 64n x 64m tile, 4x4 per thread (interleaved rows ti+16r, cols tj+16s),
// k-split(4) over grid z. grid (16,8,4) = 512 blocks -> 2 blocks/CU,
// 2 waves/SIMD for latency hiding.
__global__ __launch_bounds__(256) void fused_kernel(
    const float* __restrict__ pos, const float* __restrict__ neg,
    const float* __restrict__ w, float* __restrict__ ws)
{
    __shared__ __align__(16) float As[64][36];
    __shared__ __align__(16) float Bs[64][36];

    const int tid = threadIdx.x;
    const int n0 = blockIdx.y * 64;
    const int m0 = blockIdx.x * 64;
    const int z  = blockIdx.z;
    const float* Asrc = pos + (size_t)n0 * DIM + z * 128;
    const float* Bsrc = ((m0 < NPOS) ? (pos + (size_t)m0 * DIM)
                                     : (neg + (size_t)(m0 - NPOS) * DIM)) + z * 128;
    const float* w3 = w + 2 * DIM + z * 128;

    const int lr = tid >> 3;       // 0..31 staging row
    const int lc = (tid & 7) << 2; // 0..28 staging col
    const int ti = tid >> 4;       // 0..15
    const int tj = tid & 15;       // 0..15

    float c[4][4] = {{0.f}}, t[4][4] = {{0.f}};

    // prologue staging
    float4 a0 = *(const float4*)(Asrc + lr * DIM + lc);
    float4 a1 = *(const float4*)(Asrc + (lr + 32) * DIM + lc);
    float4 b0 = *(const float4*)(Bsrc + lr * DIM + lc);
    float4 b1 = *(const float4*)(Bsrc + (lr + 32) * DIM + lc);
    *(float4*)&As[lr][lc]      = a0;
    *(float4*)&As[lr + 32][lc] = a1;
    *(float4*)&Bs[lr][lc]      = b0;
    *(float4*)&Bs[lr + 32][lc] = b1;
    __syncthreads();

    #pragma unroll 1
    for (int iter = 0; iter < 4; ++iter) {
        const bool more = (iter < 3);
        if (more) {   // prefetch next tile into regs (hides global latency)
            const float* ap = Asrc + (iter + 1) * 32;
            const float* bp = Bsrc + (iter + 1) * 32;
            a0 = *(const float4*)(ap + lr * DIM + lc);
            a1 = *(const float4*)(ap + (lr + 32) * DIM + lc);
            b0 = *(const float4*)(bp + lr * DIM + lc);
            b1 = *(const float4*)(bp + (lr + 32) * DIM + lc);
        }
        const float* w3i = w3 + iter * 32;
        #pragma unroll
        for (int k = 0; k < 32; k += 4) {
            float4 av[4], bv[4];
            #pragma unroll
            for (int r = 0; r < 4; ++r) av[r] = *(const float4*)&As[ti + 16 * r][k];
            #pragma unroll
            for (int s = 0; s < 4; ++s) bv[s] = *(const float4*)&Bs[tj + 16 * s][k];
            const float4 wv = *(const float4*)(w3i + k);  // uniform -> s_load
            #pragma unroll
            for (int r = 0; r < 4; ++r) {
                #pragma unroll
                for (int s = 0; s < 4; ++s) {
                    c[r][s] = fmaf(av[r].x, bv[s].x, c[r][s]);
                    c[r][s] = fmaf(av[r].y, bv[s].y, c[r][s]);
                    c[r][s] = fmaf(av[r].z, bv[s].z, c[r][s]);
                    c[r][s] = fmaf(av[r].w, bv[s].w, c[r][s]);
                    t[r][s] = fmaf(fabsf(av[r].x - bv[s].x), wv.x, t[r][s]);
                    t[r][s] = fmaf(fabsf(av[r].y - bv[s].y), wv.y, t[r][s]);
                    t[r][s] = fmaf(fabsf(av[r].z - bv[s].z), wv.z, t[r][s]);
                    t[r][s] = fmaf(fabsf(av[r].w - bv[s].w), wv.w, t[r][s]);
                }
            }
        }
        if (more) {
            __syncthreads();
            *(float4*)&As[lr][lc]      = a0;
            *(float4*)&As[lr + 32][lc] = a1;
            *(float4*)&Bs[lr][lc]      = b0;
            *(float4*)&Bs[lr + 32][lc] = b1;
            __syncthreads();
        }
    }

    float* Sp = ws + OFF_P + (size_t)z * PSZ;
    float* Tp = ws + OFF_P + (size_t)(4 + z) * PSZ;
    #pragma unroll
    for (int r = 0; r < 4; ++r) {
        int n = n0 + ti + 16 * r;
        #pragma unroll
        for (int s = 0; s < 4; ++s) {
            int m = m0 + tj + 16 * s;
            Sp[(size_t)n * NB + m] = c[r][s];
            Tp[(size_t)n * NB + m] = t[r][s];
        }
    }
}

// ---------------- Kernel 3: combine partials + closs + BCE ----------------
// one wave per pos row n; 128 blocks x 256 threads.
__global__ __launch_bounds__(256) void finish_kernel(
    const float* __restrict__ lb, float* __restrict__ ws, float* __restrict__ out)
{
    const int n = blockIdx.x * 4 + (threadIdx.x >> 6);
    const int l = threadIdx.x & 63;
    const float invn = ws[OFF_INV + n];
    const float t1n  = ws[OFF_T1 + n];
    const float bias = lb[0];

    // cols: float4 index i4 = l + 64j (m = 4*i4); j=0,1 -> pos (logit_p), j=2,3 -> neg (deno)
    float4 cj[4];
    float eneg = 0.f;
    #pragma unroll
    for (int j = 0; j < 4; ++j) {
        int i4 = l + 64 * j;
        float4 sc = {0.f, 0.f, 0.f, 0.f};
        #pragma unroll
        for (int z = 0; z < 4; ++z) {
            const float4 s = ((const float4*)(ws + OFF_P + (size_t)z * PSZ + (size_t)n * NB))[i4];
            sc.x += s.x; sc.y += s.y; sc.z += s.z; sc.w += s.w;
        }
        float4 inv4 = *(const float4*)(ws + OFF_INV + 4 * i4);
        float4 cc;
        cc.x = sc.x * invn * inv4.x;
        cc.y = sc.y * invn * inv4.y;
        cc.z = sc.z * invn * inv4.z;
        cc.w = sc.w * invn * inv4.w;
        cj[j] = cc;
        if (j >= 2)
            eneg += __expf(cc.x) + __expf(cc.y) + __expf(cc.z) + __expf(cc.w);
    }
    #pragma unroll
    for (int off = 32; off; off >>= 1) eneg += __shfl_xor(eneg, off);

    float part = 0.f;
    #pragma unroll
    for (int j = 0; j < 2; ++j) {
        float4 cc = cj[j];
        part += __logf(eneg + __expf(cc.x) + EPSV) - cc.x;
        part += __logf(eneg + __expf(cc.y) + EPSV) - cc.y;
        part += __logf(eneg + __expf(cc.z) + EPSV) - cc.z;
        part += __logf(eneg + __expf(cc.w) + EPSV) - cc.w;
    }

    float bce = 0.f;
    #pragma unroll
    for (int j = 0; j < 4; ++j) {
        int i4 = l + 64 * j;
        float4 tt = {0.f, 0.f, 0.f, 0.f};
        #pragma unroll
        for (int z = 0; z < 4; ++z) {
            const float4 p = ((const float4*)(ws + OFF_P + (size_t)(4 + z) * PSZ + (size_t)n * NB))[i4];
            tt.x += p.x; tt.y += p.y; tt.z += p.z; tt.w += p.w;
        }
        float4 t2 = *(const float4*)(ws + OFF_T2 + 4 * i4);
        float4 lg;
        lg.x = t1n + t2.x + tt.x + bias;
        lg.y = t1n + t2.y + tt.y + bias;
        lg.z = t1n + t2.z + tt.z + bias;
        lg.w = t1n + t2.w + tt.w + bias;
        if (j < 2)
            bce += softplus_f(-lg.x) + softplus_f(-lg.y) + softplus_f(-lg.z) + softplus_f(-lg.w);
        else
            bce += softplus_f(lg.x) + softplus_f(lg.y) + softplus_f(lg.z) + softplus_f(lg.w);
    }
    part += bce * (1.f / 1024.f);

    #pragma unroll
    for (int off = 32; off; off >>= 1) part += __shfl_xor(part, off);
    if (l == 0) atomicAdd(out, part);
}

extern "C" void kernel_launch(void* const* d_in, const int* in_sizes, int n_in,
                              void* d_out, int out_size, void* d_ws, size_t ws_size,
                              hipStream_t stream) {
    (void)in_sizes; (void)n_in; (void)out_size; (void)ws_size;
    const float* pos = (const float*)d_in[0];
    const float* neg = (const float*)d_in[1];
    const float* w   = (const float*)d_in[2];
    const float* lb  = (const float*)d_in[3];
    float* out = (float*)d_out;
    float* ws  = (float*)d_ws;

    prep_kernel<<<256, 256, 0, stream>>>(pos, neg, w, ws, out);
    fused_kernel<<<dim3(16, 8, 4), 256, 0, stream>>>(pos, neg, w, ws);
    finish_kernel<<<128, 256, 0, stream>>>(lb, ws, out);
}